// Round 4
// baseline (4106.758 us; speedup 1.0000x reference)
//
#include <hip/hip_runtime.h>
#include <math.h>
#include <stdint.h>

typedef float f4u __attribute__((ext_vector_type(4), aligned(4)));
typedef __attribute__((ext_vector_type(8))) short short8;   // 8 bf16 (4 VGPR)
typedef __attribute__((ext_vector_type(4))) float float4v;  // MFMA acc

#define DIM 256
#define KCB 1024
#define PERP_OFF 16777217
#define ENC_OFF  16777218
#define CAP 32
#define EPS 0.004f

// ---------------------------------------------------------------------------
// numpy pairwise sum-of-squares of a 128-block (8 accumulators, pairwise
// combine); squares rounded separately; no fma contraction.
// ---------------------------------------------------------------------------
__device__ __forceinline__ float np_sumsq128(const float* a, int stride) {
  float r[8];
  #pragma unroll
  for (int j = 0; j < 8; ++j) { float v = a[j * stride]; r[j] = __fmul_rn(v, v); }
  #pragma unroll
  for (int i = 8; i < 128; i += 8) {
    #pragma unroll
    for (int j = 0; j < 8; ++j) {
      float v = a[(i + j) * stride];
      r[j] = __fadd_rn(r[j], __fmul_rn(v, v));
    }
  }
  float s01 = __fadd_rn(r[0], r[1]);
  float s23 = __fadd_rn(r[2], r[3]);
  float s45 = __fadd_rn(r[4], r[5]);
  float s67 = __fadd_rn(r[6], r[7]);
  return __fadd_rn(__fadd_rn(s01, s23), __fadd_rn(s45, s67));
}

__device__ __forceinline__ unsigned short f2bf(float f) {
  unsigned u = __float_as_uint(f);
  u += 0x7FFFu + ((u >> 16) & 1u);     // RNE
  return (unsigned short)(u >> 16);
}

// ---------------------------------------------------------------------------
// k_insq: np-exact in_sq[n]. grid 256x256 (coalesced: lanes = consecutive w)
// ---------------------------------------------------------------------------
__global__ __launch_bounds__(256)
void k_insq(const float* __restrict__ x, float* __restrict__ in_sq) {
  const int n = blockIdx.x * 256 + threadIdx.x;
  const int b = n >> 12;
  const int hw = n & 4095;
  const float* p = x + b * 1048576 + hw;
  float h0 = np_sumsq128(p, 4096);
  float h1 = np_sumsq128(p + 128 * 4096, 4096);
  in_sq[n] = __fadd_rn(h0, h1);
}

// ---------------------------------------------------------------------------
// k_prep: cb_t[d][k] (fp32, for k_epi gathers), e_bf16[k][d], np-exact
// cb_sq[k] (lane 0, row L1-hot), zero counts. grid 1024 x 64.
// ---------------------------------------------------------------------------
__global__ __launch_bounds__(64)
void k_prep(const float* __restrict__ cb, float* __restrict__ cb_t,
            unsigned short* __restrict__ e_bf16, float* __restrict__ cb_sq,
            int* __restrict__ counts) {
  const int k = blockIdx.x;
  const int l = threadIdx.x;                  // 0..63
  float4 v = ((const float4*)(cb + k * DIM))[l];
  cb_t[(l*4+0)*KCB + k] = v.x;
  cb_t[(l*4+1)*KCB + k] = v.y;
  cb_t[(l*4+2)*KCB + k] = v.z;
  cb_t[(l*4+3)*KCB + k] = v.w;
  unsigned short bs[4] = {f2bf(v.x), f2bf(v.y), f2bf(v.z), f2bf(v.w)};
  *(ushort4*)(e_bf16 + k * DIM + l * 4) = *(ushort4*)bs;
  if (l == 0) {
    const float* p = cb + k * DIM;
    cb_sq[k] = __fadd_rn(np_sumsq128(p, 1), np_sumsq128(p + 128, 1));
    counts[k] = 0;
  }
}

// ---------------------------------------------------------------------------
// k_score: bf16 MFMA approx scores s = cb_sq[k] - 2*dot_bf16 for all (n,k),
// with running-min candidate capture (s <= m_run + EPS). A = codebook
// (m=code), B = x (n=vector). Wave: n-tile 32 (2 groups of 16) x all 1024 k.
// Block 256 thr = 4 waves = 128 n. grid 512.
//   A-frag: e_bf16[(ct*16 + lane&15)*256 + ks*32 + quad*8] (16B contiguous)
//   B-frag: gathered from fp32 x (NCHW) once per wave, packed to bf16.
//   D: col=lane&15 = vector, row=quad*4+reg = code.
// ---------------------------------------------------------------------------
__global__ __launch_bounds__(256, 2)
void k_score(const float* __restrict__ x, const unsigned short* __restrict__ e_bf16,
             const float* __restrict__ cb_sq, unsigned int* __restrict__ gcnt,
             unsigned short* __restrict__ glist) {
  __shared__ unsigned int   lcnt[128];
  __shared__ unsigned short llist[128 * CAP];   // 8KB
  const int t    = threadIdx.x;
  const int wv   = t >> 6;
  const int lane = t & 63;
  const int l15  = lane & 15;
  const int quad = lane >> 4;
  if (t < 128) lcnt[t] = 0;
  __syncthreads();

  // --- B-frag setup: 2 n-groups x 8 K-steps, gathered from fp32 x ---
  short8 Bf[2][8];
  const int nbase = blockIdx.x * 128 + wv * 32;
  #pragma unroll
  for (int g = 0; g < 2; ++g) {
    const int n = nbase + g * 16 + l15;
    const float* xb = x + (n >> 12) * 1048576 + (n & 4095);
    #pragma unroll
    for (int ks = 0; ks < 8; ++ks) {
      const int d0 = ks * 32 + quad * 8;
      float f[8];
      #pragma unroll
      for (int j = 0; j < 8; ++j) f[j] = xb[(d0 + j) * 4096];
      union { unsigned short s[8]; short8 v; } u;
      #pragma unroll
      for (int j = 0; j < 8; ++j) u.s[j] = f2bf(f[j]);
      Bf[g][ks] = u.v;
    }
  }

  float m[2] = {1e30f, 1e30f};
  const int nl0 = wv * 32 + l15;      // n_local for g=0 (g=1: +16)

  for (int ct = 0; ct < 64; ++ct) {
    float4v acc0 = {0.f, 0.f, 0.f, 0.f};
    float4v acc1 = {0.f, 0.f, 0.f, 0.f};
    const unsigned short* ap = e_bf16 + (ct * 16 + l15) * DIM + quad * 8;
    #pragma unroll
    for (int ks = 0; ks < 8; ++ks) {
      const short8 a = *(const short8*)(ap + ks * 32);
      acc0 = __builtin_amdgcn_mfma_f32_16x16x32_bf16(a, Bf[0][ks], acc0, 0, 0, 0);
      acc1 = __builtin_amdgcn_mfma_f32_16x16x32_bf16(a, Bf[1][ks], acc1, 0, 0, 0);
    }
    const float4 cs = *(const float4*)(cb_sq + ct * 16 + quad * 4);
    const float csa[4] = {cs.x, cs.y, cs.z, cs.w};
    #pragma unroll
    for (int g = 0; g < 2; ++g) {
      const float sa[4] = {
        fmaf(-2.f, (g ? acc1.x : acc0.x), csa[0]),
        fmaf(-2.f, (g ? acc1.y : acc0.y), csa[1]),
        fmaf(-2.f, (g ? acc1.z : acc0.z), csa[2]),
        fmaf(-2.f, (g ? acc1.w : acc0.w), csa[3])};
      const int nl = nl0 + g * 16;
      #pragma unroll
      for (int r = 0; r < 4; ++r) {
        if (sa[r] <= m[g] + EPS) {
          unsigned slot = atomicAdd(&lcnt[nl], 1u);
          if (slot < CAP) llist[nl * CAP + slot] =
              (unsigned short)(ct * 16 + quad * 4 + r);
        }
        m[g] = fminf(m[g], sa[r]);
      }
      // share running min across the 4 quads (same n) for the next tile
      m[g] = fminf(m[g], __shfl_xor(m[g], 16));
      m[g] = fminf(m[g], __shfl_xor(m[g], 32));
    }
  }

  __syncthreads();
  if (t < 128) gcnt[blockIdx.x * 128 + t] = lcnt[t];
  // dump lists: 128*CAP*2B = 8KB = 512 uint4
  uint4* gdst = (uint4*)(glist + (size_t)blockIdx.x * 128 * CAP);
  const uint4* lsrc = (const uint4*)llist;
  gdst[t * 2]     = lsrc[t * 2];
  gdst[t * 2 + 1] = lsrc[t * 2 + 1];
}

// ---------------------------------------------------------------------------
// k_refine: np-exact fp32 dist (bitwise = R3's chain) over the candidates;
// 2 threads per n (even/odd list slots), dual chains share x loads; x reads
// fully coalesced from NCHW (consecutive n = consecutive w). grid 512 x 256.
// ---------------------------------------------------------------------------
__global__ __launch_bounds__(256)
void k_refine(const float* __restrict__ x, const float* __restrict__ cb,
              const float* __restrict__ cb_sq, const float* __restrict__ in_sq,
              const unsigned int* __restrict__ gcnt,
              const unsigned short* __restrict__ glist,
              int* __restrict__ best_idx) {
  const int tid  = blockIdx.x * 256 + threadIdx.x;
  const int n    = tid >> 1;
  const int half = tid & 1;
  const unsigned cnt = gcnt[n];
  const float* xb = x + (n >> 12) * 1048576 + (n & 4095);
  const float isq = in_sq[n];
  float bv = 1e30f; int bc = 0x7FFFFFFF;

  if (cnt <= CAP) {
    const unsigned short* lst = glist + (size_t)n * CAP;
    for (unsigned i = half; i < cnt; i += 4) {
      const int c1 = lst[i];
      const bool has2 = (i + 2) < cnt;
      const int c2 = has2 ? lst[i + 2] : c1;
      const float* e1 = cb + c1 * DIM;
      const float* e2 = cb + c2 * DIM;
      float d1 = 0.f, d2 = 0.f;
      #pragma unroll 8
      for (int d = 0; d < DIM; ++d) {
        const float xv = xb[d * 4096];
        d1 = fmaf(xv, e1[d], d1);
        d2 = fmaf(xv, e2[d], d2);
      }
      {
        const float dist = __fsub_rn(__fadd_rn(isq, cb_sq[c1]), __fmul_rn(2.f, d1));
        if (dist < bv || (dist == bv && c1 < bc)) { bv = dist; bc = c1; }
      }
      if (has2) {
        const float dist = __fsub_rn(__fadd_rn(isq, cb_sq[c2]), __fmul_rn(2.f, d2));
        if (dist < bv || (dist == bv && c2 < bc)) { bv = dist; bc = c2; }
      }
    }
  } else {
    // overflow fallback (probability ~1e-12): exact scan of all codes
    for (int c = half; c < KCB; c += 2) {
      const float* e1 = cb + c * DIM;
      float d1 = 0.f;
      #pragma unroll 8
      for (int d = 0; d < DIM; ++d) d1 = fmaf(xb[d * 4096], e1[d], d1);
      const float dist = __fsub_rn(__fadd_rn(isq, cb_sq[c]), __fmul_rn(2.f, d1));
      if (dist < bv || (dist == bv && c < bc)) { bv = dist; bc = c; }
    }
  }
  // combine the thread pair
  const float ov = __shfl_xor(bv, 1);
  const int   oc = __shfl_xor(bc, 1);
  if (ov < bv || (ov == bv && oc < bc)) { bv = ov; bc = oc; }
  if (half == 0) best_idx[n] = bc;
}

// ---------------------------------------------------------------------------
// k_epi: fused epilogue (one block per (b,h)): one-hot encodings (coalesced),
// histogram, xq straight-through + double loss partial. grid 1024 x 256.
// ---------------------------------------------------------------------------
__global__ __launch_bounds__(256)
void k_epi(const float* __restrict__ x, const float* __restrict__ cb_t,
           const int* __restrict__ best_idx, float* __restrict__ out1,
           float* __restrict__ enc, int* __restrict__ counts,
           double* __restrict__ partials) {
  const int t  = threadIdx.x;
  const int bh = blockIdx.x;
  const int b  = bh >> 6, h = bh & 63;
  __shared__ int idxs[64];
  if (t < 64) {
    const int myidx = best_idx[bh * 64 + t];
    idxs[t] = myidx;
    atomicAdd(counts + myidx, 1);
  }
  __syncthreads();

  {
    float* base = enc + (size_t)bh * 65536 + t * 4;
    #pragma unroll 8
    for (int r = 0; r < 64; ++r) {
      const int bi = idxs[r];
      f4u v = {0.f, 0.f, 0.f, 0.f};
      if ((bi >> 2) == t) {
        if ((bi & 3) == 0) v.x = 1.f; else if ((bi & 3) == 1) v.y = 1.f;
        else if ((bi & 3) == 2) v.z = 1.f; else v.w = 1.f;
      }
      *(f4u*)(base + r * 1024) = v;
    }
  }

  const int w4 = (t & 15) * 4;
  const int cg = t >> 4;
  const int i0 = idxs[w4], i1 = idxs[w4+1], i2 = idxs[w4+2], i3 = idxs[w4+3];
  double s = 0.0;
  #pragma unroll 4
  for (int j = 0; j < 16; ++j) {
    const int c = cg * 16 + j;
    const size_t off = ((size_t)b << 20) + ((size_t)c << 12) + (h << 6) + w4;
    const float4 xp = *(const float4*)(x + off);
    const float* row = cb_t + c * KCB;
    const float q0 = row[i0], q1 = row[i1], q2 = row[i2], q3 = row[i3];
    const float d0 = __fsub_rn(q0, xp.x), d1 = __fsub_rn(q1, xp.y);
    const float d2 = __fsub_rn(q2, xp.z), d3 = __fsub_rn(q3, xp.w);
    f4u o;
    o.x = __fadd_rn(xp.x, d0); o.y = __fadd_rn(xp.y, d1);
    o.z = __fadd_rn(xp.z, d2); o.w = __fadd_rn(xp.w, d3);
    *(f4u*)(out1 + off) = o;
    s += (double)(d0*d0) + (double)(d1*d1) + (double)(d2*d2) + (double)(d3*d3);
  }
  #pragma unroll
  for (int off = 32; off > 0; off >>= 1) s += __shfl_down(s, off);
  __shared__ double sm[4];
  if ((t & 63) == 0) sm[t >> 6] = s;
  __syncthreads();
  if (t == 0) partials[bh] = (sm[0] + sm[1]) + (sm[2] + sm[3]);
}

// ---------------------------------------------------------------------------
// k_final: loss + perplexity. grid 1 x 256
// ---------------------------------------------------------------------------
__global__ __launch_bounds__(256)
void k_final(const double* __restrict__ partials, const int* __restrict__ counts,
             float* __restrict__ out) {
  const int t = threadIdx.x;
  double s = 0.0;
  #pragma unroll
  for (int i = 0; i < 4; ++i) s += partials[t + i * 256];
  #pragma unroll
  for (int off = 32; off > 0; off >>= 1) s += __shfl_down(s, off);
  __shared__ double sm[4];
  __shared__ float smf[4];
  if ((t & 63) == 0) sm[t >> 6] = s;

  float ps = 0.f;
  #pragma unroll
  for (int i = 0; i < 4; ++i) {
    const float p = (float)counts[t + i * 256] * (1.0f / 65536.0f);
    ps += p * logf(1.0e10f + p);
  }
  #pragma unroll
  for (int off = 32; off > 0; off >>= 1) ps += __shfl_down(ps, off);
  if ((t & 63) == 0) smf[t >> 6] = ps;
  __syncthreads();
  if (t == 0) {
    const double tot = (sm[0] + sm[1]) + (sm[2] + sm[3]);
    const float mval = (float)(tot / 16777216.0);
    out[0] = mval + 0.25f * mval;
    out[PERP_OFF] = expf(-((smf[0] + smf[1]) + (smf[2] + smf[3])));
  }
}

// ---------------------------------------------------------------------------
extern "C" void kernel_launch(void* const* d_in, const int* in_sizes, int n_in,
                              void* d_out, int out_size, void* d_ws, size_t ws_size,
                              hipStream_t stream) {
  const float* x  = (const float*)d_in[0];   // (16,256,64,64) fp32
  const float* cb = (const float*)d_in[1];   // (1024,256) fp32
  float* out = (float*)d_out;
  char*  ws  = (char*)d_ws;

  int*            counts   = (int*)(ws + 0);                //   4 KB
  float*          cb_sq    = (float*)(ws + 4096);           //   4 KB
  int*            best_idx = (int*)(ws + 8192);             // 256 KB
  float*          in_sq    = (float*)(ws + 270336);         // 256 KB
  double*         partials = (double*)(ws + 532480);        //   8 KB
  float*          cb_t     = (float*)(ws + 540672);         //   1 MB
  unsigned short* e_bf16   = (unsigned short*)(ws + 1589248); // 512 KB
  unsigned int*   gcnt     = (unsigned int*)(ws + 2113536); // 256 KB
  unsigned short* glist    = (unsigned short*)(ws + 2375680); // 4 MB

  k_insq  <<<256, 256, 0, stream>>>(x, in_sq);
  k_prep  <<<1024, 64, 0, stream>>>(cb, cb_t, e_bf16, cb_sq, counts);
  k_score <<<512, 256, 0, stream>>>(x, e_bf16, cb_sq, gcnt, glist);
  k_refine<<<512, 256, 0, stream>>>(x, cb, cb_sq, in_sq, gcnt, glist, best_idx);
  k_epi   <<<1024, 256, 0, stream>>>(x, cb_t, best_idx, out + 1,
                                     out + ENC_OFF, counts, partials);
  k_final <<<1, 256, 0, stream>>>(partials, counts, out);
}

// Round 5
// 694.802 us; speedup vs baseline: 5.9107x; 5.9107x over previous
//
#include <hip/hip_runtime.h>
#include <math.h>
#include <stdint.h>

typedef float f4u __attribute__((ext_vector_type(4), aligned(4)));
typedef __attribute__((ext_vector_type(8))) short short8;   // 8 bf16 (4 VGPR)
typedef __attribute__((ext_vector_type(4))) float float4v;  // MFMA acc

#define DIM 256
#define KCB 1024
#define PERP_OFF 16777217
#define ENC_OFF  16777218
#define CAP 32
#define EPS 0.008f

// ---------------------------------------------------------------------------
// numpy pairwise sum-of-squares of a 128-block (8 accumulators, pairwise
// combine); squares rounded separately; no fma contraction.
// ---------------------------------------------------------------------------
__device__ __forceinline__ float np_sumsq128(const float* a, int stride) {
  float r[8];
  #pragma unroll
  for (int j = 0; j < 8; ++j) { float v = a[j * stride]; r[j] = __fmul_rn(v, v); }
  #pragma unroll
  for (int i = 8; i < 128; i += 8) {
    #pragma unroll
    for (int j = 0; j < 8; ++j) {
      float v = a[(i + j) * stride];
      r[j] = __fadd_rn(r[j], __fmul_rn(v, v));
    }
  }
  float s01 = __fadd_rn(r[0], r[1]);
  float s23 = __fadd_rn(r[2], r[3]);
  float s45 = __fadd_rn(r[4], r[5]);
  float s67 = __fadd_rn(r[6], r[7]);
  return __fadd_rn(__fadd_rn(s01, s23), __fadd_rn(s45, s67));
}

__device__ __forceinline__ unsigned short f2bf(float f) {
  unsigned u = __float_as_uint(f);
  u += 0x7FFFu + ((u >> 16) & 1u);     // RNE
  return (unsigned short)(u >> 16);
}

// ---------------------------------------------------------------------------
// k_insq: np-exact in_sq[n]. grid 256x256 (lanes = consecutive w, coalesced)
// ---------------------------------------------------------------------------
__global__ __launch_bounds__(256)
void k_insq(const float* __restrict__ x, float* __restrict__ in_sq) {
  const int n = blockIdx.x * 256 + threadIdx.x;
  const int b = n >> 12;
  const int hw = n & 4095;
  const float* p = x + b * 1048576 + hw;
  float h0 = np_sumsq128(p, 4096);
  float h1 = np_sumsq128(p + 128 * 4096, 4096);
  in_sq[n] = __fadd_rn(h0, h1);
}

// ---------------------------------------------------------------------------
// k_prep: cb_t[d][k] (fp32, for k_epi gathers), e_bf16[k][d], np-exact
// cb_sq[k] (lane 0, row L1-hot), zero counts. grid 1024 x 64.
// ---------------------------------------------------------------------------
__global__ __launch_bounds__(64)
void k_prep(const float* __restrict__ cb, float* __restrict__ cb_t,
            unsigned short* __restrict__ e_bf16, float* __restrict__ cb_sq,
            int* __restrict__ counts) {
  const int k = blockIdx.x;
  const int l = threadIdx.x;                  // 0..63
  float4 v = ((const float4*)(cb + k * DIM))[l];
  cb_t[(l*4+0)*KCB + k] = v.x;
  cb_t[(l*4+1)*KCB + k] = v.y;
  cb_t[(l*4+2)*KCB + k] = v.z;
  cb_t[(l*4+3)*KCB + k] = v.w;
  unsigned short bs[4] = {f2bf(v.x), f2bf(v.y), f2bf(v.z), f2bf(v.w)};
  *(ushort4*)(e_bf16 + k * DIM + l * 4) = *(ushort4*)bs;
  if (l == 0) {
    const float* p = cb + k * DIM;
    cb_sq[k] = __fadd_rn(np_sumsq128(p, 1), np_sumsq128(p + 128, 1));
    counts[k] = 0;
  }
}

// ---------------------------------------------------------------------------
// k_score v2 (TWO-PASS): bf16 MFMA approx scores s = cb_sq[k] - 2*dot for all
// (n,k). Pass 1: per-n min only. Pass 2: re-run identical MFMA sequence
// (bitwise-reproducible) and capture s <= m_final + EPS (expected ~1.6/n).
// Wave: 64 n (4 groups of 16) x all 1024 k; block = 4 waves = 256 n. grid 256.
//   A-frag: e_bf16[(ct*16 + l15)*256 + ks*32 + quad*8] (16B contiguous)
//   B-frag: gathered once from fp32 x (NCHW), packed bf16, held in VGPRs.
//   D: col=lane&15 = vector, row=quad*4+reg = code.  (layout HW-verified R4)
// ---------------------------------------------------------------------------
__global__ __launch_bounds__(256, 2)
void k_score(const float* __restrict__ x, const unsigned short* __restrict__ e_bf16,
             const float* __restrict__ cb_sq, unsigned int* __restrict__ gcnt,
             unsigned short* __restrict__ glist) {
  __shared__ unsigned int   lcnt[256];
  __shared__ unsigned short llist[256 * CAP];   // 16KB
  const int t    = threadIdx.x;
  const int wv   = t >> 6;
  const int lane = t & 63;
  const int l15  = lane & 15;
  const int quad = lane >> 4;
  lcnt[t] = 0;
  __syncthreads();

  // --- B-frag setup: 4 n-groups x 8 K-steps, gathered from fp32 x ---
  short8 Bf[4][8];
  const int nbase = blockIdx.x * 256 + wv * 64;
  #pragma unroll
  for (int g = 0; g < 4; ++g) {
    const int n = nbase + g * 16 + l15;
    const float* xb = x + (n >> 12) * 1048576 + (n & 4095);
    #pragma unroll
    for (int ks = 0; ks < 8; ++ks) {
      const int d0 = ks * 32 + quad * 8;
      union { unsigned short s[8]; short8 v; } u;
      #pragma unroll
      for (int j = 0; j < 8; ++j) u.s[j] = f2bf(xb[(d0 + j) * 4096]);
      Bf[g][ks] = u.v;
    }
  }

  // ---- pass 1: per-n minimum ----
  float m[4] = {1e30f, 1e30f, 1e30f, 1e30f};
  for (int ct = 0; ct < 64; ++ct) {
    float4v acc[4];
    #pragma unroll
    for (int g = 0; g < 4; ++g) acc[g] = (float4v){0.f, 0.f, 0.f, 0.f};
    const unsigned short* ap = e_bf16 + (ct * 16 + l15) * DIM + quad * 8;
    #pragma unroll
    for (int ks = 0; ks < 8; ++ks) {
      const short8 a = *(const short8*)(ap + ks * 32);
      #pragma unroll
      for (int g = 0; g < 4; ++g)
        acc[g] = __builtin_amdgcn_mfma_f32_16x16x32_bf16(a, Bf[g][ks], acc[g], 0, 0, 0);
    }
    const float4 cs = *(const float4*)(cb_sq + ct * 16 + quad * 4);
    #pragma unroll
    for (int g = 0; g < 4; ++g) {
      m[g] = fminf(m[g], fmaf(-2.f, acc[g].x, cs.x));
      m[g] = fminf(m[g], fmaf(-2.f, acc[g].y, cs.y));
      m[g] = fminf(m[g], fmaf(-2.f, acc[g].z, cs.z));
      m[g] = fminf(m[g], fmaf(-2.f, acc[g].w, cs.w));
    }
  }
  float thr[4];
  #pragma unroll
  for (int g = 0; g < 4; ++g) {
    m[g] = fminf(m[g], __shfl_xor(m[g], 16));
    m[g] = fminf(m[g], __shfl_xor(m[g], 32));
    thr[g] = m[g] + EPS;
  }

  // ---- pass 2: identical compute, capture s <= thr ----
  for (int ct = 0; ct < 64; ++ct) {
    float4v acc[4];
    #pragma unroll
    for (int g = 0; g < 4; ++g) acc[g] = (float4v){0.f, 0.f, 0.f, 0.f};
    const unsigned short* ap = e_bf16 + (ct * 16 + l15) * DIM + quad * 8;
    #pragma unroll
    for (int ks = 0; ks < 8; ++ks) {
      const short8 a = *(const short8*)(ap + ks * 32);
      #pragma unroll
      for (int g = 0; g < 4; ++g)
        acc[g] = __builtin_amdgcn_mfma_f32_16x16x32_bf16(a, Bf[g][ks], acc[g], 0, 0, 0);
    }
    const float4 cs = *(const float4*)(cb_sq + ct * 16 + quad * 4);
    #pragma unroll
    for (int g = 0; g < 4; ++g) {
      const int nl = wv * 64 + g * 16 + l15;
      const float sa[4] = {fmaf(-2.f, acc[g].x, cs.x), fmaf(-2.f, acc[g].y, cs.y),
                           fmaf(-2.f, acc[g].z, cs.z), fmaf(-2.f, acc[g].w, cs.w)};
      #pragma unroll
      for (int r = 0; r < 4; ++r) {
        if (sa[r] <= thr[g]) {
          unsigned slot = atomicAdd(&lcnt[nl], 1u);
          if (slot < CAP) llist[nl * CAP + slot] =
              (unsigned short)(ct * 16 + quad * 4 + r);
        }
      }
    }
  }

  __syncthreads();
  gcnt[blockIdx.x * 256 + t] = lcnt[t];
  // dump lists: 256*CAP*2B = 16KB = 1024 uint4
  uint4* gdst = (uint4*)(glist + (size_t)blockIdx.x * 256 * CAP);
  const uint4* lsrc = (const uint4*)llist;
  #pragma unroll
  for (int j = 0; j < 4; ++j) gdst[t * 4 + j] = lsrc[t * 4 + j];
}

// ---------------------------------------------------------------------------
// k_refine: np-exact fp32 dist (bitwise = R3's chain) over captured
// candidates; 2 threads per n, dual chains share x loads; coalesced x reads.
// grid 512 x 256.
// ---------------------------------------------------------------------------
__global__ __launch_bounds__(256)
void k_refine(const float* __restrict__ x, const float* __restrict__ cb,
              const float* __restrict__ cb_sq, const float* __restrict__ in_sq,
              const unsigned int* __restrict__ gcnt,
              const unsigned short* __restrict__ glist,
              int* __restrict__ best_idx) {
  const int tid  = blockIdx.x * 256 + threadIdx.x;
  const int n    = tid >> 1;
  const int half = tid & 1;
  const unsigned cnt = gcnt[n];
  const float* xb = x + (n >> 12) * 1048576 + (n & 4095);
  const float isq = in_sq[n];
  float bv = 1e30f; int bc = 0x7FFFFFFF;

  if (cnt <= CAP) {
    const unsigned short* lst = glist + (size_t)n * CAP;
    for (unsigned i = half; i < cnt; i += 4) {
      const int c1 = lst[i];
      const bool has2 = (i + 2) < cnt;
      const int c2 = has2 ? lst[i + 2] : c1;
      const float* e1 = cb + c1 * DIM;
      const float* e2 = cb + c2 * DIM;
      float d1 = 0.f, d2 = 0.f;
      #pragma unroll 8
      for (int d = 0; d < DIM; ++d) {
        const float xv = xb[d * 4096];
        d1 = fmaf(xv, e1[d], d1);
        d2 = fmaf(xv, e2[d], d2);
      }
      {
        const float dist = __fsub_rn(__fadd_rn(isq, cb_sq[c1]), __fmul_rn(2.f, d1));
        if (dist < bv || (dist == bv && c1 < bc)) { bv = dist; bc = c1; }
      }
      if (has2) {
        const float dist = __fsub_rn(__fadd_rn(isq, cb_sq[c2]), __fmul_rn(2.f, d2));
        if (dist < bv || (dist == bv && c2 < bc)) { bv = dist; bc = c2; }
      }
    }
  } else {
    // overflow fallback (P ~ 1e-9 over the whole problem): exact full scan
    for (int c = half; c < KCB; c += 2) {
      const float* e1 = cb + c * DIM;
      float d1 = 0.f;
      #pragma unroll 8
      for (int d = 0; d < DIM; ++d) d1 = fmaf(xb[d * 4096], e1[d], d1);
      const float dist = __fsub_rn(__fadd_rn(isq, cb_sq[c]), __fmul_rn(2.f, d1));
      if (dist < bv || (dist == bv && c < bc)) { bv = dist; bc = c; }
    }
  }
  const float ov = __shfl_xor(bv, 1);
  const int   oc = __shfl_xor(bc, 1);
  if (ov < bv || (ov == bv && oc < bc)) { bv = ov; bc = oc; }
  if (half == 0) best_idx[n] = bc;
}

// ---------------------------------------------------------------------------
// k_epi: fused epilogue (one block per (b,h)): one-hot encodings (coalesced),
// histogram, xq straight-through + double loss partial. grid 1024 x 256.
// ---------------------------------------------------------------------------
__global__ __launch_bounds__(256)
void k_epi(const float* __restrict__ x, const float* __restrict__ cb_t,
           const int* __restrict__ best_idx, float* __restrict__ out1,
           float* __restrict__ enc, int* __restrict__ counts,
           double* __restrict__ partials) {
  const int t  = threadIdx.x;
  const int bh = blockIdx.x;
  const int b  = bh >> 6, h = bh & 63;
  __shared__ int idxs[64];
  if (t < 64) {
    const int myidx = best_idx[bh * 64 + t];
    idxs[t] = myidx;
    atomicAdd(counts + myidx, 1);
  }
  __syncthreads();

  {
    float* base = enc + (size_t)bh * 65536 + t * 4;
    #pragma unroll 8
    for (int r = 0; r < 64; ++r) {
      const int bi = idxs[r];
      f4u v = {0.f, 0.f, 0.f, 0.f};
      if ((bi >> 2) == t) {
        if ((bi & 3) == 0) v.x = 1.f; else if ((bi & 3) == 1) v.y = 1.f;
        else if ((bi & 3) == 2) v.z = 1.f; else v.w = 1.f;
      }
      *(f4u*)(base + r * 1024) = v;
    }
  }

  const int w4 = (t & 15) * 4;
  const int cg = t >> 4;
  const int i0 = idxs[w4], i1 = idxs[w4+1], i2 = idxs[w4+2], i3 = idxs[w4+3];
  double s = 0.0;
  #pragma unroll 4
  for (int j = 0; j < 16; ++j) {
    const int c = cg * 16 + j;
    const size_t off = ((size_t)b << 20) + ((size_t)c << 12) + (h << 6) + w4;
    const float4 xp = *(const float4*)(x + off);
    const float* row = cb_t + c * KCB;
    const float q0 = row[i0], q1 = row[i1], q2 = row[i2], q3 = row[i3];
    const float d0 = __fsub_rn(q0, xp.x), d1 = __fsub_rn(q1, xp.y);
    const float d2 = __fsub_rn(q2, xp.z), d3 = __fsub_rn(q3, xp.w);
    f4u o;
    o.x = __fadd_rn(xp.x, d0); o.y = __fadd_rn(xp.y, d1);
    o.z = __fadd_rn(xp.z, d2); o.w = __fadd_rn(xp.w, d3);
    *(f4u*)(out1 + off) = o;
    s += (double)(d0*d0) + (double)(d1*d1) + (double)(d2*d2) + (double)(d3*d3);
  }
  #pragma unroll
  for (int off = 32; off > 0; off >>= 1) s += __shfl_down(s, off);
  __shared__ double sm[4];
  if ((t & 63) == 0) sm[t >> 6] = s;
  __syncthreads();
  if (t == 0) partials[bh] = (sm[0] + sm[1]) + (sm[2] + sm[3]);
}

// ---------------------------------------------------------------------------
// k_final: loss + perplexity. grid 1 x 256
// ---------------------------------------------------------------------------
__global__ __launch_bounds__(256)
void k_final(const double* __restrict__ partials, const int* __restrict__ counts,
             float* __restrict__ out) {
  const int t = threadIdx.x;
  double s = 0.0;
  #pragma unroll
  for (int i = 0; i < 4; ++i) s += partials[t + i * 256];
  #pragma unroll
  for (int off = 32; off > 0; off >>= 1) s += __shfl_down(s, off);
  __shared__ double sm[4];
  __shared__ float smf[4];
  if ((t & 63) == 0) sm[t >> 6] = s;

  float ps = 0.f;
  #pragma unroll
  for (int i = 0; i < 4; ++i) {
    const float p = (float)counts[t + i * 256] * (1.0f / 65536.0f);
    ps += p * logf(1.0e10f + p);
  }
  #pragma unroll
  for (int off = 32; off > 0; off >>= 1) ps += __shfl_down(ps, off);
  if ((t & 63) == 0) smf[t >> 6] = ps;
  __syncthreads();
  if (t == 0) {
    const double tot = (sm[0] + sm[1]) + (sm[2] + sm[3]);
    const float mval = (float)(tot / 16777216.0);
    out[0] = mval + 0.25f * mval;
    out[PERP_OFF] = expf(-((smf[0] + smf[1]) + (smf[2] + smf[3])));
  }
}

// ---------------------------------------------------------------------------
extern "C" void kernel_launch(void* const* d_in, const int* in_sizes, int n_in,
                              void* d_out, int out_size, void* d_ws, size_t ws_size,
                              hipStream_t stream) {
  const float* x  = (const float*)d_in[0];   // (16,256,64,64) fp32
  const float* cb = (const float*)d_in[1];   // (1024,256) fp32
  float* out = (float*)d_out;
  char*  ws  = (char*)d_ws;

  int*            counts   = (int*)(ws + 0);                //   4 KB
  float*          cb_sq    = (float*)(ws + 4096);           //   4 KB
  int*            best_idx = (int*)(ws + 8192);             // 256 KB
  float*          in_sq    = (float*)(ws + 270336);         // 256 KB
  double*         partials = (double*)(ws + 532480);        //   8 KB
  float*          cb_t     = (float*)(ws + 540672);         //   1 MB
  unsigned short* e_bf16   = (unsigned short*)(ws + 1589248); // 512 KB
  unsigned int*   gcnt     = (unsigned int*)(ws + 2113536); // 256 KB
  unsigned short* glist    = (unsigned short*)(ws + 2375680); // 4 MB

  k_insq  <<<256, 256, 0, stream>>>(x, in_sq);
  k_prep  <<<1024, 64, 0, stream>>>(cb, cb_t, e_bf16, cb_sq, counts);
  k_score <<<256, 256, 0, stream>>>(x, e_bf16, cb_sq, gcnt, glist);
  k_refine<<<512, 256, 0, stream>>>(x, cb, cb_sq, in_sq, gcnt, glist, best_idx);
  k_epi   <<<1024, 256, 0, stream>>>(x, cb_t, best_idx, out + 1,
                                     out + ENC_OFF, counts, partials);
  k_final <<<1, 256, 0, stream>>>(partials, counts, out);
}